// Round 7
// baseline (341.084 us; speedup 1.0000x reference)
//
#include <hip/hip_runtime.h>
#include <hip/hip_bf16.h>
#include <stdint.h>
#include <math.h>

typedef __bf16 bf16x8 __attribute__((ext_vector_type(8)));
typedef float f32x4 __attribute__((ext_vector_type(4)));
typedef float f32x16 __attribute__((ext_vector_type(16)));
using bf16 = __hip_bfloat16;

__device__ inline float bf2f(bf16 x) { return __bfloat162float(x); }
__device__ inline bf16 f2bf(float x) { return __float2bfloat16(x); }

__device__ inline f32x4 mfma16(bf16x8 a, bf16x8 b, f32x4 c) {
  return __builtin_amdgcn_mfma_f32_16x16x32_bf16(a, b, c, 0, 0, 0);
}
__device__ inline f32x16 mfma32(bf16x8 a, bf16x8 b, f32x16 c) {
  return __builtin_amdgcn_mfma_f32_32x32x16_bf16(a, b, c, 0, 0, 0);
}

// async global->LDS, 16B per lane. LDS dest must be wave-uniform base + lane*16.
__device__ inline void async16(const bf16* g, bf16* l) {
  __builtin_amdgcn_global_load_lds(
      (const __attribute__((address_space(1))) unsigned int*)g,
      (__attribute__((address_space(3))) unsigned int*)l, 16, 0, 0);
}

// fast GPT-2 gelu: tanh(u) = 1 - 2/(exp(2u)+1); exact limits at +-inf
__device__ inline float gelu_new(float x) {
  float u2 = 1.5957691216057308f * (x + 0.044715f * x * x * x);
  float e = __expf(u2);
  float t = 1.0f - 2.0f * __builtin_amdgcn_rcpf(e + 1.0f);
  return 0.5f * x * (1.0f + t);
}

// ---------------- LayerNorm ----------------
__global__ __launch_bounds__(256) void ln_kernel(const float* __restrict__ x,
                                                 const float* __restrict__ w,
                                                 const float* __restrict__ bb,
                                                 bf16* __restrict__ out) {
  const int D = 768;
  size_t base = (size_t)blockIdx.x * D;
  int t = threadIdx.x;
  float v0 = x[base + t];
  float v1 = x[base + t + 256];
  float v2 = x[base + t + 512];
  float s = v0 + v1 + v2;
  float ss = v0 * v0 + v1 * v1 + v2 * v2;
#pragma unroll
  for (int off = 32; off > 0; off >>= 1) {
    s += __shfl_down(s, off, 64);
    ss += __shfl_down(ss, off, 64);
  }
  __shared__ float red[8];
  int wv = t >> 6, ln = t & 63;
  if (ln == 0) { red[wv] = s; red[4 + wv] = ss; }
  __syncthreads();
  s = red[0] + red[1] + red[2] + red[3];
  ss = red[4] + red[5] + red[6] + red[7];
  float mu = s * (1.0f / 768.0f);
  float var = ss * (1.0f / 768.0f) - mu * mu;
  float rinv = rsqrtf(var + 1e-5f);
  out[base + t]       = f2bf((v0 - mu) * rinv * w[t]       + bb[t]);
  out[base + t + 256] = f2bf((v1 - mu) * rinv * w[t + 256] + bb[t + 256]);
  out[base + t + 512] = f2bf((v2 - mu) * rinv * w[t + 512] + bb[t + 512]);
}

// ---------------- tiled transposes ----------------
__global__ __launch_bounds__(256) void transpose_tiled(const float* __restrict__ in,
                                                       bf16* __restrict__ out, int R, int C) {
  __shared__ float tile[32][33];
  int tx = threadIdx.x & 31, ty = threadIdx.x >> 5;
  int r0 = blockIdx.x * 32, c0 = blockIdx.y * 32;
#pragma unroll
  for (int j = 0; j < 32; j += 8)
    tile[ty + j][tx] = in[(size_t)(r0 + ty + j) * C + c0 + tx];
  __syncthreads();
#pragma unroll
  for (int j = 0; j < 32; j += 8)
    out[(size_t)(c0 + ty + j) * R + r0 + tx] = f2bf(tile[tx][ty + j]);
}

// merged Q/K/V gather: z = which*12 + head; per-head 768x64 -> 64x768 transpose
__global__ __launch_bounds__(256) void qkv_gather3(const float* __restrict__ Wq,
                                                   const float* __restrict__ Wk,
                                                   const float* __restrict__ Wv,
                                                   bf16* __restrict__ Wt) {
  __shared__ float tile[32][33];
  int z = blockIdx.z;
  int which = z / 12, h = z - which * 12;
  const float* W = (which == 0) ? Wq : ((which == 1) ? Wk : Wv);
  const float* in = W + (size_t)h * 768 * 64;
  bf16* out = Wt + (size_t)which * 589824 + (size_t)h * 64 * 768;
  int tx = threadIdx.x & 31, ty = threadIdx.x >> 5;
  int r0 = blockIdx.x * 32, c0 = blockIdx.y * 32;
#pragma unroll
  for (int j = 0; j < 32; j += 8)
    tile[ty + j][tx] = in[(size_t)(r0 + ty + j) * 64 + c0 + tx];
  __syncthreads();
#pragma unroll
  for (int j = 0; j < 32; j += 8)
    out[(size_t)(c0 + ty + j) * 768 + r0 + tx] = f2bf(tile[tx][ty + j]);
}

__global__ __launch_bounds__(256) void pack_qkv_bias(const float* __restrict__ bq,
                                                     const float* __restrict__ bk,
                                                     const float* __restrict__ bv,
                                                     float* __restrict__ out) {
  int i = blockIdx.x * 256 + threadIdx.x;  // < 2304
  out[i] = (i < 768) ? bq[i] : ((i < 1536) ? bk[i - 768] : bv[i - 1536]);
}

// ---------------- GEMM: C[M,N] = A[M,K] * BT[N,K]^T ----------------
// 32x32x16 MFMA (2495 TF pipe vs 2176 for 16x16x32; half the issue slots).
// XOR-swizzled LDS tiles kill the 128B-row-stride bank conflict.
// C/D layout (m74/m101-verified): col=lane&31, row=(reg&3)+8*(reg>>2)+4*(lane>>5).
enum { MODE_QKV = 0, MODE_ADDF = 2, MODE_GELU = 3 };

template <int MODE, int MROWS>
__global__ __launch_bounds__(256) void gemm_bt(
    const bf16* __restrict__ A, const bf16* __restrict__ BT,
    const float* __restrict__ bias,
    const float* __restrict__ addend,
    float* __restrict__ out_f32,
    bf16* __restrict__ out_bf16,
    int M, int N, int K) {
  constexpr int SA = MROWS / 32;        // A-staging iterations
  constexpr int MI = MROWS / 64;        // 32-row compute subtiles per wave
  constexpr int HW = MROWS / 2;         // wave m-span
  constexpr int STAGE = (MROWS + 128) * 64;
  constexpr int SMEM = STAGE > 17472 ? STAGE : 17472;  // scratch: 4 waves * 2184 fp32
  __shared__ __align__(16) bf16 smem[SMEM];
  bf16* Alds = smem;
  bf16* Blds = smem + MROWS * 64;
  const int t = threadIdx.x;
  const int wave = t >> 6, lane = t & 63;
  const int l32 = lane & 31, hk = lane >> 5;
  const int wm = wave >> 1, wn = wave & 1;
  const int m0 = blockIdx.x * MROWS, n0 = blockIdx.y * 128;

  f32x16 acc[MI][2] = {};

  for (int k0 = 0; k0 < K; k0 += 64) {
#pragma unroll
    for (int i = 0; i < SA; i++) {
      int c = i * 256 + t;
      int r = c >> 3, cs = c & 7;
      async16(A + (size_t)(m0 + r) * K + k0 + ((cs ^ (r & 7)) << 3), &Alds[c * 8]);
    }
#pragma unroll
    for (int i = 0; i < 4; i++) {
      int c = i * 256 + t;
      int r = c >> 3, cs = c & 7;
      async16(BT + (size_t)(n0 + r) * K + k0 + ((cs ^ (r & 7)) << 3), &Blds[c * 8]);
    }
    __syncthreads();
#pragma unroll
    for (int kk = 0; kk < 4; kk++) {
      const int cb = kk * 2 + hk;  // 16B block index within the 64-elem row
      bf16x8 af[MI], bfr[2];
#pragma unroll
      for (int mi = 0; mi < MI; mi++)
        af[mi] = *(const bf16x8*)&Alds[(wm * HW + mi * 32 + l32) * 64 +
                                       ((cb ^ (l32 & 7)) << 3)];
#pragma unroll
      for (int ni = 0; ni < 2; ni++)
        bfr[ni] = *(const bf16x8*)&Blds[(wn * 64 + ni * 32 + l32) * 64 +
                                        ((cb ^ (l32 & 7)) << 3)];
#pragma unroll
      for (int mi = 0; mi < MI; mi++)
#pragma unroll
        for (int ni = 0; ni < 2; ni++)
          acc[mi][ni] = mfma32(af[mi], bfr[ni], acc[mi][ni]);
    }
    __syncthreads();
  }

  // ---------------- epilogue: per-wave LDS transpose -> coalesced 16B stores ----------------
  float bv[2];
#pragma unroll
  for (int ni = 0; ni < 2; ni++) bv[ni] = bias[n0 + wn * 64 + ni * 32 + l32];

  float* sc = (float*)smem + wave * 2184;  // 32x(stride 68) or 64x(stride 33)
  const bool vseg = (MODE == MODE_QKV) && ((n0 + wn * 64) >= 1536);

#pragma unroll
  for (int mi = 0; mi < MI; mi++) {
    __syncthreads();  // WAR: previous reads (k-loop or prior mi) done before overwrite
#pragma unroll
    for (int ni = 0; ni < 2; ni++)
#pragma unroll
      for (int reg = 0; reg < 16; reg++) {
        int row = (reg & 3) + 8 * (reg >> 2) + 4 * hk;  // 0..31
        float val = acc[mi][ni][reg] + bv[ni];
        if (vseg) sc[(ni * 32 + l32) * 33 + row] = val;
        else      sc[row * 68 + ni * 32 + l32] = val;
      }
    __syncthreads();  // RAW: scratch visible before cross-lane reads

    if (!vseg) {
#pragma unroll
      for (int p = 0; p < 4; p++) {
        int rl = p * 8 + (lane >> 3);
        int cl = (lane & 7) * 8;
        float v[8];
#pragma unroll
        for (int j = 0; j < 8; j++) v[j] = sc[rl * 68 + cl + j];
        int rm = m0 + wm * HW + mi * 32 + rl;
        int cn0 = n0 + wn * 64 + cl;
        if constexpr (MODE == MODE_GELU) {
          bf16x8 o;
#pragma unroll
          for (int j = 0; j < 8; j++) o[j] = (__bf16)gelu_new(v[j]);
          *(bf16x8*)(out_bf16 + (size_t)rm * N + cn0) = o;
        } else if constexpr (MODE == MODE_ADDF) {
          size_t idx = (size_t)rm * N + cn0;
          f32x4 a0 = *(const f32x4*)(addend + idx);
          f32x4 a1 = *(const f32x4*)(addend + idx + 4);
          f32x4 o0, o1;
#pragma unroll
          for (int j = 0; j < 4; j++) { o0[j] = v[j] + a0[j]; o1[j] = v[4 + j] + a1[j]; }
          *(f32x4*)(out_f32 + idx) = o0;
          *(f32x4*)(out_f32 + idx + 4) = o1;
        } else {  // MODE_QKV, seg 0/1 (Q,K): [b,h,s,e]
          int seg = cn0 / 768;
          int lnn = cn0 - seg * 768;
          int h2 = lnn >> 6, e0 = lnn & 63;
          int b2 = rm >> 10, sq = rm & 1023;
          bf16x8 o;
#pragma unroll
          for (int j = 0; j < 8; j++) o[j] = (__bf16)v[j];
          *(bf16x8*)(out_bf16 + (size_t)seg * 6291456 +
                     (((size_t)(b2 * 12 + h2) * 1024 + sq) << 6) + e0) = o;
        }
      }
    } else {
      // V chunk: scratch is [col 64][row 32 stride 33]; store [b,h,e,s] runs along s
#pragma unroll
      for (int p = 0; p < 4; p++) {
        int col = p * 16 + (lane >> 2);
        int row0 = (lane & 3) * 8;
        float v[8];
#pragma unroll
        for (int j = 0; j < 8; j++) v[j] = sc[col * 33 + row0 + j];
        int e_he = n0 + wn * 64 + col;
        int lnn = e_he - 1536;
        int h2 = lnn >> 6, e2 = lnn & 63;
        int s0 = m0 + wm * HW + mi * 32 + row0;
        int b2 = s0 >> 10, sq = s0 & 1023;
        bf16x8 o;
#pragma unroll
        for (int j = 0; j < 8; j++) o[j] = (__bf16)v[j];
        *(bf16x8*)(out_bf16 + (size_t)2 * 6291456 +
                   (((size_t)(b2 * 12 + h2) * 64 + e2) << 10) + sq) = o;
      }
    }
  }
}

// ---------------- flash attention (swizzled K/V/P tiles, 16x16 MFMA) ----------------
__global__ __launch_bounds__(256) void attn_kernel(const bf16* __restrict__ q,
                                                   const bf16* __restrict__ k,
                                                   const bf16* __restrict__ vt,
                                                   bf16* __restrict__ z) {
  const int S = 1024, E = 64;
  __shared__ __align__(16) bf16 Klds[64 * 64];
  __shared__ __align__(16) bf16 Vlds[64 * 64];
  __shared__ __align__(16) bf16 Plds[4 * 16 * 64];
  const int pb = blockIdx.x;   // 0..7
  const int bh = blockIdx.y;   // 0..95
  const int t = threadIdx.x;
  const int wave = t >> 6, lane = t & 63;
  const int lm = lane & 15, quad = lane >> 4;
  const size_t bh_se = (size_t)bh * S * E;
  const int b = bh / 12, h = bh - b * 12;

  for (int seg = 0; seg < 2; seg++) {
    const int qt = seg ? (15 - pb) : pb;
    const int qrow = qt * 64 + wave * 16 + lm;
    bf16x8 qf0 = *(const bf16x8*)(q + bh_se + (size_t)qrow * E + quad * 8);
    bf16x8 qf1 = *(const bf16x8*)(q + bh_se + (size_t)qrow * E + 32 + quad * 8);

    f32x4 acco[4] = {};
    float lsum[4] = {0.f, 0.f, 0.f, 0.f};

    for (int kt = 0; kt <= qt; kt++) {
#pragma unroll
      for (int i = 0; i < 2; i++) {
        int c = i * 256 + t;
        int r = c >> 3, cs = c & 7;
        int sw = (cs ^ (r & 7)) << 3;
        async16(k + bh_se + (size_t)(kt * 64 + r) * E + sw, &Klds[c * 8]);
        async16(vt + bh_se + (size_t)r * S + kt * 64 + sw, &Vlds[c * 8]);
      }
      __syncthreads();

      f32x4 accs[4] = {};
#pragma unroll
      for (int ni = 0; ni < 4; ni++) {
        int row = ni * 16 + lm;
        bf16x8 kf0 = *(const bf16x8*)&Klds[row * 64 + ((quad ^ (lm & 7)) << 3)];
        bf16x8 kf1 = *(const bf16x8*)&Klds[row * 64 + (((4 + quad) ^ (lm & 7)) << 3)];
        accs[ni] = mfma16(qf0, kf0, accs[ni]);
        accs[ni] = mfma16(qf1, kf1, accs[ni]);
      }

      float pv[4][4];
      const int qg = wave * 16 + quad * 4;
      if (kt == qt) {
#pragma unroll
        for (int ni = 0; ni < 4; ni++)
#pragma unroll
          for (int reg = 0; reg < 4; reg++) {
            float e_ = __expf(accs[ni][reg] * 0.125f);
            pv[ni][reg] = ((ni * 16 + lm) > (qg + reg)) ? 0.f : e_;
          }
      } else {
#pragma unroll
        for (int ni = 0; ni < 4; ni++)
#pragma unroll
          for (int reg = 0; reg < 4; reg++)
            pv[ni][reg] = __expf(accs[ni][reg] * 0.125f);
      }

#pragma unroll
      for (int ni = 0; ni < 4; ni++)
#pragma unroll
        for (int reg = 0; reg < 4; reg++) {
          lsum[reg] += pv[ni][reg];
          int pr = quad * 4 + reg;
          int ce = ni * 16 + lm;
          Plds[wave * 1024 + pr * 64 + (((ce >> 3) ^ (pr & 7)) << 3) + (ce & 7)] =
              f2bf(pv[ni][reg]);
        }
      __syncthreads();

      bf16x8 pf0 = *(const bf16x8*)&Plds[wave * 1024 + lm * 64 + ((quad ^ (lm & 7)) << 3)];
      bf16x8 pf1 = *(const bf16x8*)&Plds[wave * 1024 + lm * 64 + (((4 + quad) ^ (lm & 7)) << 3)];
#pragma unroll
      for (int ni = 0; ni < 4; ni++) {
        int row = ni * 16 + lm;
        bf16x8 vf0 = *(const bf16x8*)&Vlds[row * 64 + ((quad ^ (lm & 7)) << 3)];
        bf16x8 vf1 = *(const bf16x8*)&Vlds[row * 64 + (((4 + quad) ^ (lm & 7)) << 3)];
        acco[ni] = mfma16(pf0, vf0, acco[ni]);
        acco[ni] = mfma16(pf1, vf1, acco[ni]);
      }
      __syncthreads();
    }

#pragma unroll
    for (int reg = 0; reg < 4; reg++) {
#pragma unroll
      for (int off = 1; off < 16; off <<= 1) lsum[reg] += __shfl_xor(lsum[reg], off, 16);
    }
    float rl[4];
#pragma unroll
    for (int reg = 0; reg < 4; reg++) rl[reg] = 1.0f / lsum[reg];

#pragma unroll
    for (int ni = 0; ni < 4; ni++)
#pragma unroll
      for (int reg = 0; reg < 4; reg++) {
        int srow = qt * 64 + wave * 16 + quad * 4 + reg;
        size_t idx = (((size_t)(b * 1024 + srow) * 12 + h) << 6) + ni * 16 + lm;
        z[idx] = f2bf(acco[ni][reg] * rl[reg]);
      }
  }
}

// ---------------- launch ----------------
extern "C" void kernel_launch(void* const* d_in, const int* in_sizes, int n_in,
                              void* d_out, int out_size, void* d_ws, size_t ws_size,
                              hipStream_t stream) {
  (void)in_sizes; (void)n_in; (void)out_size; (void)ws_size;
  const float* resid_pre = (const float*)d_in[0];
  const float* ln1_w = (const float*)d_in[1];
  const float* ln1_b = (const float*)d_in[2];
  const float* W_Q = (const float*)d_in[3];
  const float* b_Q = (const float*)d_in[4];
  const float* W_K = (const float*)d_in[5];
  const float* b_K = (const float*)d_in[6];
  const float* W_V = (const float*)d_in[7];
  const float* b_V = (const float*)d_in[8];
  const float* W_O = (const float*)d_in[9];
  const float* b_O = (const float*)d_in[10];
  const float* ln2_w = (const float*)d_in[11];
  const float* ln2_b = (const float*)d_in[12];
  const float* W_in = (const float*)d_in[13];
  const float* b_in = (const float*)d_in[14];
  const float* W_out = (const float*)d_in[15];
  const float* b_out = (const float*)d_in[16];

  char* ws = (char*)d_ws;
  const size_t EB = (size_t)8192 * 768;
  bf16* n1     = (bf16*)(ws);
  bf16* qb     = (bf16*)(ws + EB * 2);   // q, k, vt contiguous (EB elements each)
  bf16* zb     = (bf16*)(ws + EB * 8);
  float* resid = (float*)(ws + EB * 10);
  bf16* act    = (bf16*)(ws + EB * 2);   // reuse q..z region post-attention
  char* wsw = ws + EB * 14;
  bf16* Wqkv_t = (bf16*)(wsw);           // [2304,768]: Wq_t | Wk_t | Wv_t
  bf16* Wo_t   = (bf16*)(wsw + 3 * 1179648);
  bf16* Win_t  = (bf16*)(wsw + 4 * 1179648);
  bf16* Wout_t = (bf16*)(wsw + 4 * 1179648 + 4718592);
  float* bias_qkv = (float*)(wsw + 4 * 1179648 + 4718592 + 9437184);
  bf16* kb  = qb + EB;
  bf16* vtb = qb + 2 * EB;

  qkv_gather3<<<dim3(24, 2, 36), 256, 0, stream>>>(W_Q, W_K, W_V, Wqkv_t);
  transpose_tiled<<<dim3(24, 24), 256, 0, stream>>>(W_O, Wo_t, 768, 768);
  transpose_tiled<<<dim3(24, 96), 256, 0, stream>>>(W_in, Win_t, 768, 3072);
  transpose_tiled<<<dim3(96, 24), 256, 0, stream>>>(W_out, Wout_t, 3072, 768);
  pack_qkv_bias<<<9, 256, 0, stream>>>(b_Q, b_K, b_V, bias_qkv);

  ln_kernel<<<8192, 256, 0, stream>>>(resid_pre, ln1_w, ln1_b, n1);

  gemm_bt<MODE_QKV, 128><<<dim3(64, 18), 256, 0, stream>>>(
      n1, Wqkv_t, bias_qkv, nullptr, nullptr, qb, 8192, 2304, 768);

  attn_kernel<<<dim3(8, 96), 256, 0, stream>>>(qb, kb, vtb, zb);

  gemm_bt<MODE_ADDF, 64><<<dim3(128, 6), 256, 0, stream>>>(
      zb, Wo_t, b_O, resid_pre, resid, nullptr, 8192, 768, 768);

  ln_kernel<<<8192, 256, 0, stream>>>(resid, ln2_w, ln2_b, n1);

  gemm_bt<MODE_GELU, 128><<<dim3(64, 24), 256, 0, stream>>>(
      n1, Win_t, b_in, nullptr, nullptr, act, 8192, 3072, 768);
  gemm_bt<MODE_ADDF, 64><<<dim3(128, 6), 256, 0, stream>>>(
      act, Wout_t, b_out, resid, (float*)d_out, nullptr, 8192, 768, 3072);
}

// Round 8
// 333.861 us; speedup vs baseline: 1.0216x; 1.0216x over previous
//
#include <hip/hip_runtime.h>
#include <hip/hip_bf16.h>
#include <stdint.h>
#include <math.h>

typedef __bf16 bf16x8 __attribute__((ext_vector_type(8)));
typedef float f32x4 __attribute__((ext_vector_type(4)));
using bf16 = __hip_bfloat16;

__device__ inline float bf2f(bf16 x) { return __bfloat162float(x); }
__device__ inline bf16 f2bf(float x) { return __float2bfloat16(x); }

__device__ inline f32x4 mfma16(bf16x8 a, bf16x8 b, f32x4 c) {
  return __builtin_amdgcn_mfma_f32_16x16x32_bf16(a, b, c, 0, 0, 0);
}

// async global->LDS, 16B per lane. LDS dest must be wave-uniform base + lane*16.
__device__ inline void async16(const bf16* g, bf16* l) {
  __builtin_amdgcn_global_load_lds(
      (const __attribute__((address_space(1))) unsigned int*)g,
      (__attribute__((address_space(3))) unsigned int*)l, 16, 0, 0);
}

// fast GPT-2 gelu: tanh(u) = 1 - 2/(exp(2u)+1); exact limits at +-inf
__device__ inline float gelu_new(float x) {
  float u2 = 1.5957691216057308f * (x + 0.044715f * x * x * x);
  float e = __expf(u2);
  float t = 1.0f - 2.0f * __builtin_amdgcn_rcpf(e + 1.0f);
  return 0.5f * x * (1.0f + t);
}

// ---------------- LayerNorm body (used by prep_all and ln_kernel) ----------------
__device__ inline void ln_body(const float* __restrict__ x, const float* __restrict__ w,
                               const float* __restrict__ bb, bf16* __restrict__ out,
                               int row, int t, float* red) {
  size_t base = (size_t)row * 768;
  float v0 = x[base + t];
  float v1 = x[base + t + 256];
  float v2 = x[base + t + 512];
  float s = v0 + v1 + v2;
  float ss = v0 * v0 + v1 * v1 + v2 * v2;
#pragma unroll
  for (int off = 32; off > 0; off >>= 1) {
    s += __shfl_down(s, off, 64);
    ss += __shfl_down(ss, off, 64);
  }
  int wv = t >> 6, ln = t & 63;
  if (ln == 0) { red[wv] = s; red[4 + wv] = ss; }
  __syncthreads();
  s = red[0] + red[1] + red[2] + red[3];
  ss = red[4] + red[5] + red[6] + red[7];
  float mu = s * (1.0f / 768.0f);
  float var = ss * (1.0f / 768.0f) - mu * mu;
  float rinv = rsqrtf(var + 1e-5f);
  out[base + t]       = f2bf((v0 - mu) * rinv * w[t]       + bb[t]);
  out[base + t + 256] = f2bf((v1 - mu) * rinv * w[t + 256] + bb[t + 256]);
  out[base + t + 512] = f2bf((v2 - mu) * rinv * w[t + 512] + bb[t + 512]);
}

__global__ __launch_bounds__(256) void ln_kernel(const float* __restrict__ x,
                                                 const float* __restrict__ w,
                                                 const float* __restrict__ bb,
                                                 bf16* __restrict__ out) {
  __shared__ float red[8];
  ln_body(x, w, bb, out, blockIdx.x, threadIdx.x, red);
}

// ---------------- transpose body: fp32 in[R][C] -> bf16 out[C][R], 32x32 tile ----------------
__device__ inline void transpose_body(const float* __restrict__ in, bf16* __restrict__ out,
                                      int R, int C, int bx, int by, int t,
                                      float (*tile)[33]) {
  int tx = t & 31, ty = t >> 5;
  int r0 = bx * 32, c0 = by * 32;
#pragma unroll
  for (int j = 0; j < 32; j += 8)
    tile[ty + j][tx] = in[(size_t)(r0 + ty + j) * C + c0 + tx];
  __syncthreads();
#pragma unroll
  for (int j = 0; j < 32; j += 8)
    out[(size_t)(c0 + ty + j) * R + r0 + tx] = f2bf(tile[tx][ty + j]);
}

// ---------------- merged prep: LN1 + all weight transposes + bias pack ----------------
__global__ __launch_bounds__(256) void prep_all(
    const float* __restrict__ resid_pre, const float* __restrict__ ln1_w,
    const float* __restrict__ ln1_b, bf16* __restrict__ n1,
    const float* __restrict__ Wq, const float* __restrict__ Wk,
    const float* __restrict__ Wv, bf16* __restrict__ Wqkv_t,
    const float* __restrict__ W_O, bf16* __restrict__ Wo_t,
    const float* __restrict__ W_in, bf16* __restrict__ Win_t,
    const float* __restrict__ W_out, bf16* __restrict__ Wout_t,
    const float* __restrict__ bq, const float* __restrict__ bk,
    const float* __restrict__ bv, float* __restrict__ bias_qkv) {
  __shared__ float tile[32][33];
  const int t = threadIdx.x;
  int bid = blockIdx.x;
  if (bid < 8192) {                      // LN1
    ln_body(resid_pre, ln1_w, ln1_b, n1, bid, t, &tile[0][0]);
    return;
  }
  bid -= 8192;
  if (bid < 1728) {                      // QKV gather: per-head 768x64 -> 64x768
    int z = bid / 48, r = bid - z * 48;
    int which = z / 12, h = z - which * 12;
    const float* W = (which == 0) ? Wq : ((which == 1) ? Wk : Wv);
    transpose_body(W + (size_t)h * 768 * 64,
                   Wqkv_t + (size_t)which * 589824 + (size_t)h * 64 * 768,
                   768, 64, r % 24, r / 24, t, tile);
    return;
  }
  bid -= 1728;
  if (bid < 576) {                       // W_O [768,768] -> [768,768]^T
    transpose_body(W_O, Wo_t, 768, 768, bid % 24, bid / 24, t, tile);
    return;
  }
  bid -= 576;
  if (bid < 2304) {                      // W_in [768,3072] -> [3072,768]
    transpose_body(W_in, Win_t, 768, 3072, bid % 24, bid / 24, t, tile);
    return;
  }
  bid -= 2304;
  if (bid < 2304) {                      // W_out [3072,768] -> [768,3072]
    transpose_body(W_out, Wout_t, 3072, 768, bid % 96, bid / 96, t, tile);
    return;
  }
  bid -= 2304;
  int i = bid * 256 + t;                 // bias pack, 9 blocks
  if (i < 2304)
    bias_qkv[i] = (i < 768) ? bq[i] : ((i < 1536) ? bk[i - 768] : bv[i - 1536]);
}

// ---------------- GEMM: C[M,N] = A[M,K] * BT[N,K]^T (16x16x32, xor-swizzled LDS) ----------------
enum { MODE_QKV = 0, MODE_ADDF = 2, MODE_GELU = 3 };

template <int MODE, int MROWS>
__global__ __launch_bounds__(256) void gemm_bt(
    const bf16* __restrict__ A, const bf16* __restrict__ BT,
    const float* __restrict__ bias,
    const float* __restrict__ addend,
    float* __restrict__ out_f32,
    bf16* __restrict__ out_bf16,
    int M, int N, int K) {
  constexpr int MI = MROWS / 32;
  __shared__ __align__(16) bf16 smem[(MROWS + 128) * 64];
  bf16* Alds = smem;
  bf16* Blds = smem + MROWS * 64;
  const int t = threadIdx.x;
  const int wave = t >> 6, lane = t & 63;
  const int lm = lane & 15, quad = lane >> 4;
  const int wm = wave >> 1, wn = wave & 1;
  const int m0 = blockIdx.x * MROWS, n0 = blockIdx.y * 128;

  f32x4 acc[MI][4] = {};

  for (int k0 = 0; k0 < K; k0 += 64) {
#pragma unroll
    for (int i = 0; i < MI; i++) {
      int c = i * 256 + t;
      int r = c >> 3, cs = c & 7;
      async16(A + (size_t)(m0 + r) * K + k0 + ((cs ^ (r & 7)) << 3), &Alds[c * 8]);
    }
#pragma unroll
    for (int i = 0; i < 4; i++) {
      int c = i * 256 + t;
      int r = c >> 3, cs = c & 7;
      async16(BT + (size_t)(n0 + r) * K + k0 + ((cs ^ (r & 7)) << 3), &Blds[c * 8]);
    }
    __syncthreads();
#pragma unroll
    for (int kk = 0; kk < 64; kk += 32) {
      const int cbase = kk >> 3;  // 0 or 4
      bf16x8 af[MI], bfr[4];
#pragma unroll
      for (int mi = 0; mi < MI; mi++)
        af[mi] = *(const bf16x8*)&Alds[(wm * (MROWS / 2) + mi * 16 + lm) * 64 +
                                       (((cbase + quad) ^ (lm & 7)) << 3)];
#pragma unroll
      for (int ni = 0; ni < 4; ni++)
        bfr[ni] = *(const bf16x8*)&Blds[(wn * 64 + ni * 16 + lm) * 64 +
                                        (((cbase + quad) ^ (lm & 7)) << 3)];
#pragma unroll
      for (int mi = 0; mi < MI; mi++)
#pragma unroll
        for (int ni = 0; ni < 4; ni++)
          acc[mi][ni] = mfma16(af[mi], bfr[ni], acc[mi][ni]);
    }
    __syncthreads();
  }

  // ---------------- epilogue: per-wave LDS transpose -> coalesced 16B stores ----------------
  float bv[4];
#pragma unroll
  for (int ni = 0; ni < 4; ni++) bv[ni] = bias[n0 + wn * 64 + ni * 16 + lm];

  float* sc = (float*)smem + wave * 1088;  // 16x67 (row-major) or 64x17 (V-transposed)
  const bool vseg = (MODE == MODE_QKV) && ((n0 + wn * 64) >= 1536);

#pragma unroll
  for (int mi = 0; mi < MI; mi++) {
    __syncthreads();  // WAR: previous reads done before overwriting scratch
#pragma unroll
    for (int ni = 0; ni < 4; ni++)
#pragma unroll
      for (int reg = 0; reg < 4; reg++) {
        float val = acc[mi][ni][reg] + bv[ni];
        if (vseg) sc[(ni * 16 + lm) * 17 + quad * 4 + reg] = val;
        else      sc[(quad * 4 + reg) * 67 + ni * 16 + lm] = val;
      }
    __syncthreads();  // RAW: scratch writes visible before cross-lane reads

    if (!vseg) {
#pragma unroll
      for (int p = 0; p < 2; p++) {
        int rl = p * 8 + (lane >> 3);
        int cl = (lane & 7) * 8;
        float v[8];
#pragma unroll
        for (int j = 0; j < 8; j++) v[j] = sc[rl * 67 + cl + j];
        int rm = m0 + wm * (MROWS / 2) + mi * 16 + rl;
        int cn0 = n0 + wn * 64 + cl;
        if constexpr (MODE == MODE_GELU) {
          bf16x8 o;
#pragma unroll
          for (int j = 0; j < 8; j++) o[j] = (__bf16)gelu_new(v[j]);
          *(bf16x8*)(out_bf16 + (size_t)rm * N + cn0) = o;
        } else if constexpr (MODE == MODE_ADDF) {
          size_t idx = (size_t)rm * N + cn0;
          f32x4 a0 = *(const f32x4*)(addend + idx);
          f32x4 a1 = *(const f32x4*)(addend + idx + 4);
          f32x4 o0, o1;
#pragma unroll
          for (int j = 0; j < 4; j++) { o0[j] = v[j] + a0[j]; o1[j] = v[4 + j] + a1[j]; }
          *(f32x4*)(out_f32 + idx) = o0;
          *(f32x4*)(out_f32 + idx + 4) = o1;
        } else {  // MODE_QKV, seg 0/1 (Q,K): [b,h,s,e]; Q pre-scaled by 1/sqrt(d)
          int seg = cn0 / 768;
          int lnn = cn0 - seg * 768;
          int h2 = lnn >> 6, e0 = lnn & 63;
          int b2 = rm >> 10, sq = rm & 1023;
          float scale = (seg == 0) ? 0.125f : 1.0f;
          bf16x8 o;
#pragma unroll
          for (int j = 0; j < 8; j++) o[j] = (__bf16)(v[j] * scale);
          *(bf16x8*)(out_bf16 + (size_t)seg * 6291456 +
                     (((size_t)(b2 * 12 + h2) * 1024 + sq) << 6) + e0) = o;
        }
      }
    } else {
      // V chunk: scratch is [e_local 64][s_local 16]; store [b,h,e,s] runs along s
#pragma unroll
      for (int p = 0; p < 2; p++) {
        float v[8];
#pragma unroll
        for (int j = 0; j < 8; j++) v[j] = sc[lane * 17 + p * 8 + j];
        int e_he = n0 + wn * 64 + lane;
        int lnn = e_he - 1536;
        int h2 = lnn >> 6, e2 = lnn & 63;
        int s0 = m0 + wm * (MROWS / 2) + mi * 16 + p * 8;
        int b2 = s0 >> 10, sq = s0 & 1023;
        bf16x8 o;
#pragma unroll
        for (int j = 0; j < 8; j++) o[j] = (__bf16)v[j];
        *(bf16x8*)(out_bf16 + (size_t)2 * 6291456 +
                   (((size_t)(b2 * 12 + h2) * 64 + e2) << 10) + sq) = o;
      }
    }
  }
}

// ---------------- flash attention (swizzled K/V/P tiles; Q pre-scaled) ----------------
__global__ __launch_bounds__(256) void attn_kernel(const bf16* __restrict__ q,
                                                   const bf16* __restrict__ k,
                                                   const bf16* __restrict__ vt,
                                                   bf16* __restrict__ z) {
  const int S = 1024, E = 64;
  __shared__ __align__(16) bf16 Klds[64 * 64];
  __shared__ __align__(16) bf16 Vlds[64 * 64];
  __shared__ __align__(16) bf16 Plds[4 * 16 * 64];
  const int pb = blockIdx.x;   // 0..7
  const int bh = blockIdx.y;   // 0..95
  const int t = threadIdx.x;
  const int wave = t >> 6, lane = t & 63;
  const int lm = lane & 15, quad = lane >> 4;
  const size_t bh_se = (size_t)bh * S * E;
  const int b = bh / 12, h = bh - b * 12;

  for (int seg = 0; seg < 2; seg++) {
    const int qt = seg ? (15 - pb) : pb;
    const int qrow = qt * 64 + wave * 16 + lm;
    bf16x8 qf0 = *(const bf16x8*)(q + bh_se + (size_t)qrow * E + quad * 8);
    bf16x8 qf1 = *(const bf16x8*)(q + bh_se + (size_t)qrow * E + 32 + quad * 8);

    f32x4 acco[4] = {};
    float lsum[4] = {0.f, 0.f, 0.f, 0.f};

    for (int kt = 0; kt <= qt; kt++) {
#pragma unroll
      for (int i = 0; i < 2; i++) {
        int c = i * 256 + t;
        int r = c >> 3, cs = c & 7;
        int sw = (cs ^ (r & 7)) << 3;
        async16(k + bh_se + (size_t)(kt * 64 + r) * E + sw, &Klds[c * 8]);
        async16(vt + bh_se + (size_t)r * S + kt * 64 + sw, &Vlds[c * 8]);
      }
      __syncthreads();

      f32x4 accs[4] = {};
#pragma unroll
      for (int ni = 0; ni < 4; ni++) {
        int row = ni * 16 + lm;
        bf16x8 kf0 = *(const bf16x8*)&Klds[row * 64 + ((quad ^ (lm & 7)) << 3)];
        bf16x8 kf1 = *(const bf16x8*)&Klds[row * 64 + (((4 + quad) ^ (lm & 7)) << 3)];
        accs[ni] = mfma16(qf0, kf0, accs[ni]);
        accs[ni] = mfma16(qf1, kf1, accs[ni]);
      }

      float pv[4][4];
      const int qg = wave * 16 + quad * 4;
      if (kt == qt) {
#pragma unroll
        for (int ni = 0; ni < 4; ni++)
#pragma unroll
          for (int reg = 0; reg < 4; reg++) {
            float e_ = __expf(accs[ni][reg]);
            pv[ni][reg] = ((ni * 16 + lm) > (qg + reg)) ? 0.f : e_;
          }
      } else {
#pragma unroll
        for (int ni = 0; ni < 4; ni++)
#pragma unroll
          for (int reg = 0; reg < 4; reg++)
            pv[ni][reg] = __expf(accs[ni][reg]);
      }

#pragma unroll
      for (int ni = 0; ni < 4; ni++)
#pragma unroll
        for (int reg = 0; reg < 4; reg++) {
          lsum[reg] += pv[ni][reg];
          int pr = quad * 4 + reg;
          int ce = ni * 16 + lm;
          Plds[wave * 1024 + pr * 64 + (((ce >> 3) ^ (pr & 7)) << 3) + (ce & 7)] =
              f2bf(pv[ni][reg]);
        }
      __syncthreads();

      bf16x8 pf0 = *(const bf16x8*)&Plds[wave * 1024 + lm * 64 + ((quad ^ (lm & 7)) << 3)];
      bf16x8 pf1 = *(const bf16x8*)&Plds[wave * 1024 + lm * 64 + (((4 + quad) ^ (lm & 7)) << 3)];
#pragma unroll
      for (int ni = 0; ni < 4; ni++) {
        int row = ni * 16 + lm;
        bf16x8 vf0 = *(const bf16x8*)&Vlds[row * 64 + ((quad ^ (lm & 7)) << 3)];
        bf16x8 vf1 = *(const bf16x8*)&Vlds[row * 64 + (((4 + quad) ^ (lm & 7)) << 3)];
        acco[ni] = mfma16(pf0, vf0, acco[ni]);
        acco[ni] = mfma16(pf1, vf1, acco[ni]);
      }
      __syncthreads();
    }

#pragma unroll
    for (int reg = 0; reg < 4; reg++) {
#pragma unroll
      for (int off = 1; off < 16; off <<= 1) lsum[reg] += __shfl_xor(lsum[reg], off, 16);
    }
    float rl[4];
#pragma unroll
    for (int reg = 0; reg < 4; reg++) rl[reg] = 1.0f / lsum[reg];

#pragma unroll
    for (int ni = 0; ni < 4; ni++)
#pragma unroll
      for (int reg = 0; reg < 4; reg++) {
        int srow = qt * 64 + wave * 16 + quad * 4 + reg;
        size_t idx = (((size_t)(b * 1024 + srow) * 12 + h) << 6) + ni * 16 + lm;
        z[idx] = f2bf(acco[ni][reg] * rl[reg]);
      }
  }
}

// ---------------- launch ----------------
extern "C" void kernel_launch(void* const* d_in, const int* in_sizes, int n_in,
                              void* d_out, int out_size, void* d_ws, size_t ws_size,
                              hipStream_t stream) {
  (void)in_sizes; (void)n_in; (void)out_size; (void)ws_size;
  const float* resid_pre = (const float*)d_in[0];
  const float* ln1_w = (const float*)d_in[1];
  const float* ln1_b = (const float*)d_in[2];
  const float* W_Q = (const float*)d_in[3];
  const float* b_Q = (const float*)d_in[4];
  const float* W_K = (const float*)d_in[5];
  const float* b_K = (const float*)d_in[6];
  const float* W_V = (const float*)d_in[7];
  const float* b_V = (const float*)d_in[8];
  const float* W_O = (const float*)d_in[9];
  const float* b_O = (const float*)d_in[10];
  const float* ln2_w = (const float*)d_in[11];
  const float* ln2_b = (const float*)d_in[12];
  const float* W_in = (const float*)d_in[13];
  const float* b_in = (const float*)d_in[14];
  const float* W_out = (const float*)d_in[15];
  const float* b_out = (const float*)d_in[16];

  char* ws = (char*)d_ws;
  const size_t EB = (size_t)8192 * 768;
  bf16* n1     = (bf16*)(ws);
  bf16* qb     = (bf16*)(ws + EB * 2);   // q, k, vt contiguous (EB elements each)
  bf16* zb     = (bf16*)(ws + EB * 8);
  float* resid = (float*)(ws + EB * 10);
  bf16* act    = (bf16*)(ws + EB * 2);   // reuse q..z region post-attention
  char* wsw = ws + EB * 14;
  bf16* Wqkv_t = (bf16*)(wsw);           // [2304,768]: Wq_t | Wk_t | Wv_t
  bf16* Wo_t   = (bf16*)(wsw + 3 * 1179648);
  bf16* Win_t  = (bf16*)(wsw + 4 * 1179648);
  bf16* Wout_t = (bf16*)(wsw + 4 * 1179648 + 4718592);
  float* bias_qkv = (float*)(wsw + 4 * 1179648 + 4718592 + 9437184);
  bf16* kb  = qb + EB;
  bf16* vtb = qb + 2 * EB;

  // merged: LN1 + QKV gathers + W_O/W_in/W_out transposes + bias pack
  prep_all<<<15113, 256, 0, stream>>>(resid_pre, ln1_w, ln1_b, n1,
                                      W_Q, W_K, W_V, Wqkv_t,
                                      W_O, Wo_t, W_in, Win_t, W_out, Wout_t,
                                      b_Q, b_K, b_V, bias_qkv);

  gemm_bt<MODE_QKV, 128><<<dim3(64, 18), 256, 0, stream>>>(
      n1, Wqkv_t, bias_qkv, nullptr, nullptr, qb, 8192, 2304, 768);

  attn_kernel<<<dim3(8, 96), 256, 0, stream>>>(qb, kb, vtb, zb);

  gemm_bt<MODE_ADDF, 64><<<dim3(128, 6), 256, 0, stream>>>(
      zb, Wo_t, b_O, resid_pre, resid, nullptr, 8192, 768, 768);

  ln_kernel<<<8192, 256, 0, stream>>>(resid, ln2_w, ln2_b, n1);

  gemm_bt<MODE_GELU, 128><<<dim3(64, 24), 256, 0, stream>>>(
      n1, Win_t, b_in, nullptr, nullptr, act, 8192, 3072, 768);
  gemm_bt<MODE_ADDF, 64><<<dim3(128, 6), 256, 0, stream>>>(
      act, Wout_t, b_out, resid, (float*)d_out, nullptr, 8192, 768, 3072);
}